// Round 1
// baseline (3193.501 us; speedup 1.0000x reference)
//
#include <hip/hip_runtime.h>

#define NUM_USERS 200000
#define NUM_ITEMS 100000
#define NN (NUM_USERS + NUM_ITEMS)   // 300000
#define D 32
#define NE 9600000
#define TOTAL (NN * D)               // 9,600,000 floats

// ---------------------------------------------------------------------------
// init: x0 = concat(user_w, item_w); acc = x0. float4-vectorized.
// NUM_USERS*D = 6,400,000 is divisible by 4 so the user/item boundary is
// float4-aligned.
__global__ __launch_bounds__(256) void init_x_acc(
    const float4* __restrict__ user_w, const float4* __restrict__ item_w,
    float4* __restrict__ x, float4* __restrict__ acc) {
    int i = blockIdx.x * 256 + threadIdx.x;          // float4 index
    const int total4 = TOTAL / 4;                    // 2,400,000
    const int ub4 = (NUM_USERS * D) / 4;             // 1,600,000
    if (i < total4) {
        float4 v = (i < ub4) ? user_w[i] : item_w[i - ub4];
        x[i] = v;
        acc[i] = v;
    }
}

// ---------------------------------------------------------------------------
// SpMM scatter: one edge per 32 lanes (lane = feature d).
// y[row][d] += val * x[col][d]   via fp32 atomics (low contention: rows are
// uniform-random over 300K).
__global__ __launch_bounds__(256) void spmm_atomic(
    const int* __restrict__ rows, const int* __restrict__ cols,
    const float* __restrict__ vals, const float* __restrict__ x,
    float* __restrict__ y) {
    int t = blockIdx.x * 256 + threadIdx.x;
    int e = t >> 5;
    int d = t & 31;
    if (e < NE) {
        int r = rows[e];
        int c = cols[e];
        float v = vals[e];
        atomicAdd(&y[r * D + d], v * x[c * D + d]);
    }
}

// ---------------------------------------------------------------------------
// acc += y   (float4-vectorized streaming pass)
__global__ __launch_bounds__(256) void acc_add(
    float4* __restrict__ acc, const float4* __restrict__ y) {
    int i = blockIdx.x * 256 + threadIdx.x;
    if (i < TOTAL / 4) {
        float4 a = acc[i];
        float4 b = y[i];
        a.x += b.x; a.y += b.y; a.z += b.z; a.w += b.w;
        acc[i] = a;
    }
}

// ---------------------------------------------------------------------------
// acc *= 0.25  (final mean over the 4 accumulated terms)
__global__ __launch_bounds__(256) void scale_acc(float4* __restrict__ acc) {
    int i = blockIdx.x * 256 + threadIdx.x;
    if (i < TOTAL / 4) {
        float4 a = acc[i];
        a.x *= 0.25f; a.y *= 0.25f; a.z *= 0.25f; a.w *= 0.25f;
        acc[i] = a;
    }
}

extern "C" void kernel_launch(void* const* d_in, const int* in_sizes, int n_in,
                              void* d_out, int out_size, void* d_ws, size_t ws_size,
                              hipStream_t stream) {
    const int*   rows   = (const int*)d_in[0];
    const int*   cols   = (const int*)d_in[1];
    const float* vals   = (const float*)d_in[2];
    const float* user_w = (const float*)d_in[3];
    const float* item_w = (const float*)d_in[4];

    float* acc = (float*)d_out;                 // N*D fp32 accumulator == output layout
    float* x   = (float*)d_ws;                  // current layer input  (38.4 MB)
    float* y   = x + (size_t)TOTAL;             // next layer output    (38.4 MB)

    const int vec_blocks = (TOTAL / 4 + 255) / 256;     // 9375
    const int spmm_blocks = (NE * 32) / 256;            // 1,200,000 exactly

    init_x_acc<<<vec_blocks, 256, 0, stream>>>(
        (const float4*)user_w, (const float4*)item_w, (float4*)x, (float4*)acc);

    for (int layer = 0; layer < 3; ++layer) {
        hipMemsetAsync(y, 0, (size_t)TOTAL * sizeof(float), stream);
        spmm_atomic<<<spmm_blocks, 256, 0, stream>>>(rows, cols, vals, x, y);
        acc_add<<<vec_blocks, 256, 0, stream>>>((float4*)acc, (const float4*)y);
        // swap x <-> y for the next layer
        float* t = x; x = y; y = t;
    }

    scale_acc<<<vec_blocks, 256, 0, stream>>>((float4*)acc);
}

// Round 2
// 2766.662 us; speedup vs baseline: 1.1543x; 1.1543x over previous
//
#include <hip/hip_runtime.h>

#define NUM_USERS 200000
#define NUM_ITEMS 100000
#define NN (NUM_USERS + NUM_ITEMS)   // 300000
#define D 32
#define NE 9600000
#define TOTAL (NN * D)               // 9,600,000 floats

// ---------------------------------------------------------------------------
// init: x0 = concat(user_w, item_w); acc = x0. float4-vectorized.
__global__ __launch_bounds__(256) void init_x_acc(
    const float4* __restrict__ user_w, const float4* __restrict__ item_w,
    float4* __restrict__ x, float4* __restrict__ acc) {
    int i = blockIdx.x * 256 + threadIdx.x;          // float4 index
    const int total4 = TOTAL / 4;                    // 2,400,000
    const int ub4 = (NUM_USERS * D) / 4;             // 1,600,000
    if (i < total4) {
        float4 v = (i < ub4) ? user_w[i] : item_w[i - ub4];
        x[i] = v;
        acc[i] = v;
    }
}

// ---------------------------------------------------------------------------
// CSR build step 1: degree histogram. counts must be pre-zeroed.
__global__ __launch_bounds__(256) void hist_kernel(
    const int* __restrict__ rows, int* __restrict__ counts) {
    int e = blockIdx.x * 256 + threadIdx.x;
    if (e < NE) atomicAdd(&counts[rows[e]], 1);
}

// ---------------------------------------------------------------------------
// CSR build step 2: exclusive scan of counts -> row_start[NN+1] and a working
// copy fill_pos[NN]. Single block of 1024 threads; each thread owns a
// contiguous chunk of ~293 counters. ~2.4 MB through one CU — fine once.
__global__ __launch_bounds__(1024) void scan_kernel(
    const int* __restrict__ counts, int* __restrict__ row_start,
    int* __restrict__ fill_pos) {
    __shared__ int lds[1024];
    const int T = 1024;
    const int CH = (NN + T - 1) / T;                 // 293
    int t = threadIdx.x;
    int begin = t * CH;
    int end = begin + CH; if (end > NN) end = NN;
    int s = 0;
    for (int i = begin; i < end; ++i) s += counts[i];
    lds[t] = s;
    __syncthreads();
    // Hillis-Steele inclusive scan over the 1024 per-thread sums
    for (int off = 1; off < T; off <<= 1) {
        int v = (t >= off) ? lds[t - off] : 0;
        __syncthreads();
        lds[t] += v;
        __syncthreads();
    }
    int run = lds[t] - s;                            // exclusive prefix of this chunk
    for (int i = begin; i < end; ++i) {
        row_start[i] = run;
        fill_pos[i] = run;
        run += counts[i];
    }
    if (t == T - 1) row_start[NN] = run;             // == NE
}

// ---------------------------------------------------------------------------
// CSR build step 3: scatter (col,val) pairs into row-grouped storage.
__global__ __launch_bounds__(256) void scatter_kernel(
    const int* __restrict__ rows, const int* __restrict__ cols,
    const float* __restrict__ vals, int* __restrict__ fill_pos,
    int2* __restrict__ colval) {
    int e = blockIdx.x * 256 + threadIdx.x;
    if (e < NE) {
        int r = rows[e];
        int p = atomicAdd(&fill_pos[r], 1);
        int2 cv;
        cv.x = cols[e];
        cv.y = __float_as_int(vals[e]);
        colval[p] = cv;
    }
}

// ---------------------------------------------------------------------------
// Atomic-free SpMM: one 32-lane half-wave per row (lane = feature d).
// Gathers x[col] as coalesced 128 B reads, accumulates in registers,
// writes y[row] once, and fuses acc += y (and *0.25 on the last layer).
// Unrolled by 2 for two outstanding gathers per iteration.
template <bool LAST>
__global__ __launch_bounds__(256) void spmm_csr(
    const int* __restrict__ row_start, const int2* __restrict__ colval,
    const float* __restrict__ x, float* __restrict__ y,
    float* __restrict__ acc) {
    int lane = threadIdx.x & 31;
    int row = blockIdx.x * 8 + (threadIdx.x >> 5);   // 8 rows per 256-thread block
    if (row >= NN) return;
    int s = row_start[row];
    int e = row_start[row + 1];
    float sum = 0.f, sum2 = 0.f;
    int i = s;
    for (; i + 1 < e; i += 2) {
        int2 a = colval[i];
        int2 b = colval[i + 1];
        sum  += __int_as_float(a.y) * x[a.x * D + lane];
        sum2 += __int_as_float(b.y) * x[b.x * D + lane];
    }
    if (i < e) {
        int2 a = colval[i];
        sum += __int_as_float(a.y) * x[a.x * D + lane];
    }
    sum += sum2;
    int idx = row * D + lane;
    y[idx] = sum;
    float a = acc[idx] + sum;
    acc[idx] = LAST ? a * 0.25f : a;
}

extern "C" void kernel_launch(void* const* d_in, const int* in_sizes, int n_in,
                              void* d_out, int out_size, void* d_ws, size_t ws_size,
                              hipStream_t stream) {
    const int*   rows   = (const int*)d_in[0];
    const int*   cols   = (const int*)d_in[1];
    const float* vals   = (const float*)d_in[2];
    const float* user_w = (const float*)d_in[3];
    const float* item_w = (const float*)d_in[4];

    float* acc = (float*)d_out;                      // N*D fp32, == output layout

    // d_ws layout (4-byte elements):
    //   x:        [0, 9.6M)
    //   y:        [9.6M, 19.2M)
    //   colval:   [19.2M, 38.4M)   (int2, 8-byte aligned at byte offset 76.8MB)
    //   counts:   [38.4M, +300000)
    //   row_start:[.., +300001)
    //   fill_pos: [.., +300000)
    float* x = (float*)d_ws;
    float* y = x + (size_t)TOTAL;
    int2*  colval = (int2*)(y + (size_t)TOTAL);
    int*   counts = (int*)(colval + (size_t)NE);
    int*   row_start = counts + NN;
    int*   fill_pos = row_start + (NN + 1);

    const int vec_blocks  = (TOTAL / 4 + 255) / 256; // 9375
    const int edge_blocks = (NE + 255) / 256;        // 37500
    const int row_blocks  = (NN + 7) / 8;            // 37500

    init_x_acc<<<vec_blocks, 256, 0, stream>>>(
        (const float4*)user_w, (const float4*)item_w, (float4*)x, (float4*)acc);

    // Build CSR (per call — inputs may change between calls)
    hipMemsetAsync(counts, 0, (size_t)NN * sizeof(int), stream);
    hist_kernel<<<edge_blocks, 256, 0, stream>>>(rows, counts);
    scan_kernel<<<1, 1024, 0, stream>>>(counts, row_start, fill_pos);
    scatter_kernel<<<edge_blocks, 256, 0, stream>>>(rows, cols, vals, fill_pos, colval);

    // 3 propagation layers, atomic-free
    spmm_csr<false><<<row_blocks, 256, 0, stream>>>(row_start, colval, x, y, acc);
    spmm_csr<false><<<row_blocks, 256, 0, stream>>>(row_start, colval, y, x, acc);
    spmm_csr<true ><<<row_blocks, 256, 0, stream>>>(row_start, colval, x, y, acc);
}